// Round 15
// baseline (1488.708 us; speedup 1.0000x reference)
//
#include <hip/hip_runtime.h>
#include <cstdint>
#include <cstddef>

typedef _Float16 f16;
typedef _Float16 half2_t __attribute__((ext_vector_type(2)));
typedef _Float16 half4_t __attribute__((ext_vector_type(4)));
typedef _Float16 half8_t __attribute__((ext_vector_type(8)));
typedef float floatx4 __attribute__((ext_vector_type(4)));

__device__ __forceinline__ float fdot2u(uint32_t w, uint32_t h, float acc) {
#if __has_builtin(__builtin_amdgcn_fdot2)
    return __builtin_amdgcn_fdot2(__builtin_bit_cast(half2_t, w),
                                  __builtin_bit_cast(half2_t, h), acc, false);
#else
    half2_t a = __builtin_bit_cast(half2_t, w);
    half2_t b = __builtin_bit_cast(half2_t, h);
    return acc + (float)a[0] * (float)b[0] + (float)a[1] * (float)b[1];
#endif
}

// relaxed spin; freshness established by a single ACQUIRE fence after the spin.
// Exit target is a compile-path-fixed value -> all threads make the same decision (safe).
__device__ __forceinline__ void spin_ge(int* f, int v) {
    while (__hip_atomic_load(f, __ATOMIC_RELAXED, __HIP_MEMORY_SCOPE_AGENT) < v)
        __builtin_amdgcn_s_sleep(16);
}

__device__ __forceinline__ void acq_fence() {
    __builtin_amdgcn_fence(__ATOMIC_ACQUIRE, "agent");
}

// ---------------- fp32 -> f16 conversion ----------------
__global__ void cvt_kernel(const float* __restrict__ in, f16* __restrict__ out, int n4) {
    int i = blockIdx.x * blockDim.x + threadIdx.x;
    int stride = gridDim.x * blockDim.x;
    const float4* in4 = (const float4*)in;
    for (; i < n4; i += stride) {
        float4 v = in4[i];
        half4_t h = {(f16)v.x, (f16)v.y, (f16)v.z, (f16)v.w};
        *(half4_t*)&out[(size_t)i * 4] = h;
    }
}

// ---------------- bias sum ----------------
__global__ void bsum_kernel(const float* __restrict__ a, const float* __restrict__ b,
                            float* __restrict__ o) {
    int i = threadIdx.x;
    o[i] = a[i] + b[i];
}

// ---------------- pack W (round-7/8 layout, proven) ----------------
// 512 threads. tid: w = tid>>6, jsub = (tid>>3)&7, kg = tid&7.
// j = w*64 + jsub*8 + r; k = kg*64 + c*8 + 2q (+par).  idx = c*32 + r*4 + q.
// idx < 224 (c<7): registers, wp[idx*512 + tid];  c == 7: LDS, wp[224*512 + (r*512+tid)*4 + q].
__global__ void pack_whh(const float* __restrict__ W, uint32_t* __restrict__ wp) {
    int id = blockIdx.x * 256 + threadIdx.x;   // 131072 pairs
    int j = id >> 8;
    int kp = id & 255;
    int k = kp * 2;
    int w = j >> 6, jsub = (j >> 3) & 7, r = j & 7;
    int kg = k >> 6, c = (k >> 3) & 7, q = (k >> 1) & 3;
    int tid = w * 64 + jsub * 8 + kg;
    int idx = c * 32 + r * 4 + q;
    uint32_t lo = (uint32_t)__builtin_bit_cast(uint16_t, (f16)W[(size_t)j * 512 + k]);
    uint32_t hi = (uint32_t)__builtin_bit_cast(uint16_t, (f16)W[(size_t)j * 512 + k + 1]);
    size_t off;
    if (idx < 224) off = (size_t)idx * 512 + tid;
    else           off = (size_t)224 * 512 + ((size_t)(r * 512 + tid)) * 4 + q;
    wp[off] = (hi << 16) | lo;
}

// ---------------- xproj GEMM for layer 0 (proven) ----------------
__global__ __launch_bounds__(256) void gemm_xp(const f16* __restrict__ A,
                                               const f16* __restrict__ Bw,
                                               const float* __restrict__ bias,
                                               f16* __restrict__ C) {
    const int bn = blockIdx.x & 3;
    const int bm = blockIdx.x >> 2;
    const int tid = threadIdx.x;
    const int w = tid >> 6, l = tid & 63;
    const int wr = w >> 1, wc = w & 1;
    __shared__ f16 As[128 * 32];
    __shared__ f16 Bs[128 * 32];
    floatx4 acc[4][4] = {};
    const int lr = l & 15, lk = (l >> 4) * 8;
    for (int kk = 0; kk < 512; kk += 32) {
        __syncthreads();
        uint4 av[2], bv[2];
#pragma unroll
        for (int s = 0; s < 2; ++s) {
            int chunk = tid + s * 256;
            int row = chunk >> 2;
            int colh = (chunk & 3) * 8;
            av[s] = *(const uint4*)&A[((size_t)(bm * 128 + row)) * 512 + kk + colh];
            bv[s] = *(const uint4*)&Bw[((size_t)(bn * 128 + row)) * 512 + kk + colh];
        }
#pragma unroll
        for (int s = 0; s < 2; ++s) {
            int chunk = tid + s * 256;
            *(uint4*)&As[chunk * 8] = av[s];
            *(uint4*)&Bs[chunk * 8] = bv[s];
        }
        __syncthreads();
        half8_t af[4], bf[4];
#pragma unroll
        for (int m = 0; m < 4; ++m)
            af[m] = *(const half8_t*)&As[(wr * 64 + m * 16 + lr) * 32 + lk];
#pragma unroll
        for (int n = 0; n < 4; ++n)
            bf[n] = *(const half8_t*)&Bs[(wc * 64 + n * 16 + lr) * 32 + lk];
#pragma unroll
        for (int m = 0; m < 4; ++m)
#pragma unroll
            for (int n = 0; n < 4; ++n)
                acc[m][n] = __builtin_amdgcn_mfma_f32_16x16x32_f16(af[m], bf[n], acc[m][n], 0, 0, 0);
    }
    float bz[4];
#pragma unroll
    for (int n = 0; n < 4; ++n) bz[n] = bias[bn * 128 + wc * 64 + n * 16 + lr];
    const int lq = l >> 4;
#pragma unroll
    for (int m = 0; m < 4; ++m)
#pragma unroll
        for (int n = 0; n < 4; ++n)
#pragma unroll
            for (int e = 0; e < 4; ++e) {
                int row = bm * 128 + wr * 64 + m * 16 + lq * 4 + e;
                int col = bn * 128 + wc * 64 + n * 16 + lr;
                C[(size_t)row * 512 + col] = (f16)(acc[m][n][e] + bz[n]);
            }
}

// ---------------- fused 3-stage pipeline, XCD-segregated, 8-step chunks, 4-deep ----------------
#define FOR_Q(M, c, r) M(c, r, 0) M(c, r, 1) M(c, r, 2) M(c, r, 3)
#define FOR_R8(M, c) FOR_Q(M, c, 0) FOR_Q(M, c, 1) FOR_Q(M, c, 2) FOR_Q(M, c, 3) \
                     FOR_Q(M, c, 4) FOR_Q(M, c, 5) FOR_Q(M, c, 6) FOR_Q(M, c, 7)
#define FOR_ALL(M) FOR_R8(M, 0) FOR_R8(M, 1) FOR_R8(M, 2) FOR_R8(M, 3) \
                   FOR_R8(M, 4) FOR_R8(M, 5) FOR_R8(M, 6)

#define DECLW(c, r, q) uint32_t W_##c##_##r##_##q;
#define LOADW(c, r, q) W_##c##_##r##_##q = wpb[(size_t)(((c)*32 + (r)*4 + (q)) * 512) + tid];
#define DOTQ(c, r, q) a##r = fdot2u(W_##c##_##r##_##q, hq##q, a##r);

#define CHUNK(c)                                                   \
    {                                                              \
        uint4 hv = *(const uint4*)(hrow + (c) * 4);                \
        uint32_t hq0 = hv.x, hq1 = hv.y, hq2 = hv.z, hq3 = hv.w;   \
        FOR_R8(DOTQ, c)                                            \
    }

#define LROW(r)                                                    \
    {                                                              \
        uint4 wv = *(const uint4*)&wlds[((r) * 512 + tid) * 4];    \
        a##r = fdot2u(wv.x, hq0, a##r);                            \
        a##r = fdot2u(wv.y, hq1, a##r);                            \
        a##r = fdot2u(wv.z, hq2, a##r);                            \
        a##r = fdot2u(wv.w, hq3, a##r);                            \
    }

#define CHUNKL                                                     \
    {                                                              \
        uint4 hv = *(const uint4*)(hrow + 7 * 4);                  \
        uint32_t hq0 = hv.x, hq1 = hv.y, hq2 = hv.z, hq3 = hv.w;   \
        LROW(0) LROW(1) LROW(2) LROW(3)                            \
        LROW(4) LROW(5) LROW(6) LROW(7)                            \
    }

#define TREE8                                                                 \
    float b0 = (m0 ? a1 : a0) + __shfl_xor(m0 ? a0 : a1, 1);                  \
    float b1 = (m0 ? a3 : a2) + __shfl_xor(m0 ? a2 : a3, 1);                  \
    float b2 = (m0 ? a5 : a4) + __shfl_xor(m0 ? a4 : a5, 1);                  \
    float b3 = (m0 ? a7 : a6) + __shfl_xor(m0 ? a6 : a7, 1);                  \
    float c0 = (m1 ? b1 : b0) + __shfl_xor(m1 ? b0 : b1, 2);                  \
    float c1 = (m1 ? b3 : b2) + __shfl_xor(m1 ? b2 : b3, 2);                  \
    float d0 = (m2 ? c1 : c0) + __shfl_xor(m2 ? c0 : c1, 4);

#define HB_STRIDE 72    // 64 f16 + 8 pad per k-group: bank-conflict-free uint4 reads
#define XROW 576        // xin row stride in f16 = 8 k-groups x 72

// 256 blocks; xcd = bid&7: {0,1}->stage0, {2,3}->stage1(proj), {4,5}->stage2, {6,7} exit.
// flags count completed 8-step chunks (0..64), memset 0 per launch.
// Producer: RELEASE flag store (wb). Consumer: ACQUIRE fence after spin (inv), on consumer XCDs only.
// xin is 4-deep: mandatory blocking fetch of chunk c+1, opportunistic fetch up to c+3 using a
// tid0->LDS flag snapshot published through a barrier (uniform across waves -> no divergence).
__global__ __launch_bounds__(512)
__attribute__((amdgpu_waves_per_eu(2, 2)))
void fused3(const f16* __restrict__ xp0, const uint32_t* __restrict__ wp0,
            const uint32_t* __restrict__ wpih1, const uint32_t* __restrict__ wp1,
            const float* __restrict__ bs1,
            f16* __restrict__ h0seq, f16* __restrict__ xp1seq,
            f16* __restrict__ h1last,
            int* __restrict__ flag1, int* __restrict__ flag2) {
    const int xcd = blockIdx.x & 7;
    if (xcd >= 6) return;
    const int stage = xcd >> 1;                  // 0,1,2
    const int row = (xcd & 1) * 32 + (blockIdx.x >> 3);   // 0..63, unique per stage
    const int tid = threadIdx.x;
    const int kg = tid & 7;
    __shared__ alignas(16) f16 hbuf[2][8 * HB_STRIDE];
    __shared__ uint32_t wlds[8 * 512 * 4];            // 64 KB
    __shared__ alignas(16) f16 xin[4][8 * XROW];      // 36 KB, 4-deep 8-step chunks
    __shared__ int availLds;

    const uint32_t* wpb = (stage == 0) ? wp0 : (stage == 1) ? wpih1 : wp1;
    const f16* inbase = (stage == 0) ? xp0 + (size_t)row * 262144
                       : (stage == 1) ? h0seq + (size_t)row * 262144
                                      : xp1seq + (size_t)row * 262144;
    f16* outbase = (stage == 0) ? h0seq + (size_t)row * 262144
                  : (stage == 1) ? xp1seq + (size_t)row * 262144
                                 : h1last + (size_t)row * 512;
    int* flIn  = (stage == 1) ? flag1 + row : (stage == 2) ? flag2 + row : nullptr;
    int* flOut = (stage == 0) ? flag1 + row : (stage == 1) ? flag2 + row : nullptr;

    // stage one 8-step chunk g into padded xin[g&3]: 1 uint4 load + 1 b128 LDS write per thread.
    // tid: rw = tid>>6 (0..7), pos = tid&63 (16B units); f16 src (g*8+rw)*512 + pos*8
    // -> xin f16 idx rw*XROW + (pos>>3)*72 + (pos&7)*8
    auto stageChunk = [&](int g) {
        int rw = tid >> 6, pos = tid & 63;
        uint4 v = *(const uint4*)&inbase[(size_t)(g * 8 + rw) * 512 + pos * 8];
        *(uint4*)&xin[g & 3][rw * XROW + (pos >> 3) * 72 + (pos & 7) * 8] = v;
    };

    FOR_ALL(DECLW)
    FOR_ALL(LOADW)
#pragma unroll
    for (int i = 0; i < 8; ++i) {
        uint4 v = *(const uint4*)&wpb[(size_t)224 * 512 + (size_t)(i * 512 + tid) * 4];
        *(uint4*)&wlds[(i * 512 + tid) * 4] = v;
    }
    for (int i = tid; i < 2 * 8 * HB_STRIDE; i += 512) ((f16*)hbuf)[i] = (f16)0.f;
    float bsv = (stage == 1) ? bs1[tid] : 0.f;

    if (flIn) {
        spin_ge(flIn, 1);
        acq_fence();
    }
    stageChunk(0);
    __syncthreads();

    const bool m0 = (tid & 1), m1 = (tid & 2), m2 = (tid & 4);
    const int hwpos = (tid >> 6) * HB_STRIDE + (tid & 63);

    if (stage == 1) {
        // ---- projection: barrier-free within each 8-step chunk ----
        int fetched = 0, availB = 1;   // availB: flag snapshot from previous chunk boundary
        for (int c = 0; c < 64; ++c) {
            for (int lt = 0; lt < 8; ++lt) {
                if (lt == 4) {
                    if (fetched < c + 1 && c < 63) {       // mandatory (fixed target: safe)
                        spin_ge(flIn, c + 2);
                        acq_fence();
                        stageChunk(c + 1);
                        fetched = c + 1;
                    }
                    int lim = (c + 3 < 63) ? c + 3 : 63;   // opportunistic (uniform availB)
                    int target = (availB - 1 < lim) ? availB - 1 : lim;
                    if (target > fetched) {
                        acq_fence();
                        for (int g = fetched + 1; g <= target; ++g) stageChunk(g);
                        fetched = target;
                    }
                }
                float a0 = 0.f, a1 = 0.f, a2 = 0.f, a3 = 0.f;
                float a4 = 0.f, a5 = 0.f, a6 = 0.f, a7 = 0.f;
                const uint32_t* hrow = (const uint32_t*)&xin[c & 3][lt * XROW + kg * 72];
                CHUNKL
                CHUNK(0) CHUNK(1) CHUNK(2) CHUNK(3) CHUNK(4) CHUNK(5) CHUNK(6)
                TREE8
                outbase[(size_t)(c * 8 + lt) * 512 + tid] = (f16)(d0 + bsv);
            }
            if (tid == 0)
                availLds = __hip_atomic_load(flIn, __ATOMIC_RELAXED, __HIP_MEMORY_SCOPE_AGENT);
            __syncthreads();                           // drains stores + publishes availLds
            availB = availLds;
            if (tid == 0)
                __hip_atomic_store(flOut, c + 1, __ATOMIC_RELEASE, __HIP_MEMORY_SCOPE_AGENT);
        }
    } else {
        // ---- recurrence stages (R8 core): one barrier per step ----
        int p = 0, fetched = 0;
        for (int t = 0; t < 512; ++t) {
            const int c = t >> 3, lt = t & 7;
            if (flIn) {
                if (lt == 3 && tid == 0)
                    availLds = __hip_atomic_load(flIn, __ATOMIC_RELAXED, __HIP_MEMORY_SCOPE_AGENT);
                if (lt == 4) {                          // availLds published by step-3 barrier
                    if (fetched < c + 1 && c < 63) {    // mandatory (fixed target: safe)
                        spin_ge(flIn, c + 2);
                        acq_fence();
                        stageChunk(c + 1);
                        fetched = c + 1;
                    }
                    int lim = (c + 3 < 63) ? c + 3 : 63;
                    int target = (availLds - 1 < lim) ? availLds - 1 : lim;
                    if (target > fetched) {
                        acq_fence();
                        for (int g = fetched + 1; g <= target; ++g) stageChunk(g);
                        fetched = target;
                    }
                }
            } else {
                if (lt == 4 && c < 63) stageChunk(c + 1);   // stage 0: input static, 1-ahead
            }
            float xpv = (float)xin[c & 3][lt * XROW + (tid >> 6) * 72 + (tid & 63)];

            float a0 = 0.f, a1 = 0.f, a2 = 0.f, a3 = 0.f;
            float a4 = 0.f, a5 = 0.f, a6 = 0.f, a7 = 0.f;
            const uint32_t* hrow = (const uint32_t*)&hbuf[p][kg * HB_STRIDE];
            CHUNKL
            CHUNK(0) CHUNK(1) CHUNK(2) CHUNK(3) CHUNK(4) CHUNK(5) CHUNK(6)
            TREE8
            float s = d0 + xpv;
            float e = __expf(2.0f * s);
            f16 hh = (f16)(1.0f - 2.0f / (1.0f + e));
            hbuf[p ^ 1][hwpos] = hh;
            if (stage == 0) outbase[(size_t)t * 512 + tid] = hh;
            else if (t == 511) outbase[tid] = hh;
            __syncthreads();                           // drains global stores too
            if (stage == 0 && lt == 7 && tid == 0)
                __hip_atomic_store(flOut, c + 1, __ATOMIC_RELEASE, __HIP_MEMORY_SCOPE_AGENT);
            p ^= 1;
        }
    }
}

// ---------------- final FC ----------------
__global__ __launch_bounds__(512) void fc_kernel(const f16* __restrict__ h1,
                                                 const float* __restrict__ Wfc,
                                                 const float* __restrict__ bfc,
                                                 float* __restrict__ out) {
    int b = blockIdx.x, tid = threadIdx.x;
    __shared__ float red[8];
    float v = (float)h1[(size_t)b * 512 + tid] * Wfc[tid];
#pragma unroll
    for (int off = 32; off > 0; off >>= 1) v += __shfl_down(v, off, 64);
    if ((tid & 63) == 0) red[tid >> 6] = v;
    __syncthreads();
    if (tid == 0) {
        float s = bfc[0];
#pragma unroll
        for (int g = 0; g < 8; ++g) s += red[g];
        out[b] = s;
    }
}

extern "C" void kernel_launch(void* const* d_in, const int* in_sizes, int n_in,
                              void* d_out, int out_size, void* d_ws, size_t ws_size,
                              hipStream_t stream) {
    const float* x    = (const float*)d_in[0];
    const float* Wih0 = (const float*)d_in[1];
    const float* Whh0 = (const float*)d_in[2];
    const float* bih0 = (const float*)d_in[3];
    const float* bhh0 = (const float*)d_in[4];
    const float* Wih1 = (const float*)d_in[5];
    const float* Whh1 = (const float*)d_in[6];
    const float* bih1 = (const float*)d_in[7];
    const float* bhh1 = (const float*)d_in[8];
    const float* Wfc  = (const float*)d_in[9];
    const float* bfc  = (const float*)d_in[10];
    float* out = (float*)d_out;

    char* ws = (char*)d_ws;
    size_t off = 0;
    auto alloc = [&](size_t bytes) -> void* {
        void* p = ws + off;
        off += (bytes + 255) & ~(size_t)255;
        return p;
    };
    const size_t MTD = (size_t)64 * 512 * 512;
    f16* x16    = (f16*)alloc(MTD * 2);
    f16* h016   = (f16*)alloc(MTD * 2);
    f16* xpb    = (f16*)alloc(MTD * 2);
    f16* xp1b   = (f16*)alloc(MTD * 2);
    f16* wih016 = (f16*)alloc((size_t)512 * 512 * 2);
    uint32_t* wp0   = (uint32_t*)alloc((size_t)131072 * 4);
    uint32_t* wp1   = (uint32_t*)alloc((size_t)131072 * 4);
    uint32_t* wpih1 = (uint32_t*)alloc((size_t)131072 * 4);
    float* bs0 = (float*)alloc(512 * 4);
    float* bs1 = (float*)alloc(512 * 4);
    f16* h1last = (f16*)alloc((size_t)64 * 512 * 2);
    int* flags = (int*)alloc(128 * 4);   // flag1[64] + flag2[64]

    // prep
    cvt_kernel<<<2048, 256, 0, stream>>>(x, x16, (int)(MTD / 4));
    cvt_kernel<<<256, 256, 0, stream>>>(Wih0, wih016, 512 * 512 / 4);
    bsum_kernel<<<1, 512, 0, stream>>>(bih0, bhh0, bs0);
    bsum_kernel<<<1, 512, 0, stream>>>(bih1, bhh1, bs1);
    pack_whh<<<512, 256, 0, stream>>>(Whh0, wp0);
    pack_whh<<<512, 256, 0, stream>>>(Whh1, wp1);
    pack_whh<<<512, 256, 0, stream>>>(Wih1, wpih1);
    (void)hipMemsetAsync(flags, 0, 128 * 4, stream);

    // layer-0 xproj GEMM, then the fused 3-stage pipeline, then the head
    gemm_xp<<<1024, 256, 0, stream>>>(x16, wih016, bs0, xpb);
    fused3<<<256, 512, 0, stream>>>(xpb, wp0, wpih1, wp1, bs1,
                                    h016, xp1b, h1last, flags, flags + 64);
    fc_kernel<<<64, 512, 0, stream>>>(h1last, Wfc, bfc, out);
}

// Round 16
// 1171.341 us; speedup vs baseline: 1.2709x; 1.2709x over previous
//
#include <hip/hip_runtime.h>
#include <cstdint>
#include <cstddef>

typedef _Float16 f16;
typedef _Float16 half2_t __attribute__((ext_vector_type(2)));
typedef _Float16 half4_t __attribute__((ext_vector_type(4)));
typedef _Float16 half8_t __attribute__((ext_vector_type(8)));
typedef float floatx4 __attribute__((ext_vector_type(4)));

__device__ __forceinline__ float fdot2u(uint32_t w, uint32_t h, float acc) {
#if __has_builtin(__builtin_amdgcn_fdot2)
    return __builtin_amdgcn_fdot2(__builtin_bit_cast(half2_t, w),
                                  __builtin_bit_cast(half2_t, h), acc, false);
#else
    half2_t a = __builtin_bit_cast(half2_t, w);
    half2_t b = __builtin_bit_cast(half2_t, h);
    return acc + (float)a[0] * (float)b[0] + (float)a[1] * (float)b[1];
#endif
}

// relaxed spin; freshness established by a single ACQUIRE fence after the spin
__device__ __forceinline__ void spin_ge(int* f, int v) {
    while (__hip_atomic_load(f, __ATOMIC_RELAXED, __HIP_MEMORY_SCOPE_AGENT) < v)
        __builtin_amdgcn_s_sleep(16);
}

__device__ __forceinline__ void acq_fence() {
    __builtin_amdgcn_fence(__ATOMIC_ACQUIRE, "agent");
}

// ---------------- fp32 -> f16 conversion ----------------
__global__ void cvt_kernel(const float* __restrict__ in, f16* __restrict__ out, int n4) {
    int i = blockIdx.x * blockDim.x + threadIdx.x;
    int stride = gridDim.x * blockDim.x;
    const float4* in4 = (const float4*)in;
    for (; i < n4; i += stride) {
        float4 v = in4[i];
        half4_t h = {(f16)v.x, (f16)v.y, (f16)v.z, (f16)v.w};
        *(half4_t*)&out[(size_t)i * 4] = h;
    }
}

// ---------------- bias sum ----------------
__global__ void bsum_kernel(const float* __restrict__ a, const float* __restrict__ b,
                            float* __restrict__ o) {
    int i = threadIdx.x;
    o[i] = a[i] + b[i];
}

// ---------------- pack W (round-7/8 layout, proven) ----------------
// 512 threads. tid: w = tid>>6, jsub = (tid>>3)&7, kg = tid&7.
// j = w*64 + jsub*8 + r; k = kg*64 + c*8 + 2q (+par).  idx = c*32 + r*4 + q.
// idx < 224 (c<7): registers, wp[idx*512 + tid];  c == 7: LDS, wp[224*512 + (r*512+tid)*4 + q].
__global__ void pack_whh(const float* __restrict__ W, uint32_t* __restrict__ wp) {
    int id = blockIdx.x * 256 + threadIdx.x;   // 131072 pairs
    int j = id >> 8;
    int kp = id & 255;
    int k = kp * 2;
    int w = j >> 6, jsub = (j >> 3) & 7, r = j & 7;
    int kg = k >> 6, c = (k >> 3) & 7, q = (k >> 1) & 3;
    int tid = w * 64 + jsub * 8 + kg;
    int idx = c * 32 + r * 4 + q;
    uint32_t lo = (uint32_t)__builtin_bit_cast(uint16_t, (f16)W[(size_t)j * 512 + k]);
    uint32_t hi = (uint32_t)__builtin_bit_cast(uint16_t, (f16)W[(size_t)j * 512 + k + 1]);
    size_t off;
    if (idx < 224) off = (size_t)idx * 512 + tid;
    else           off = (size_t)224 * 512 + ((size_t)(r * 512 + tid)) * 4 + q;
    wp[off] = (hi << 16) | lo;
}

// ---------------- xproj GEMM for layer 0 (proven) ----------------
__global__ __launch_bounds__(256) void gemm_xp(const f16* __restrict__ A,
                                               const f16* __restrict__ Bw,
                                               const float* __restrict__ bias,
                                               f16* __restrict__ C) {
    const int bn = blockIdx.x & 3;
    const int bm = blockIdx.x >> 2;
    const int tid = threadIdx.x;
    const int w = tid >> 6, l = tid & 63;
    const int wr = w >> 1, wc = w & 1;
    __shared__ f16 As[128 * 32];
    __shared__ f16 Bs[128 * 32];
    floatx4 acc[4][4] = {};
    const int lr = l & 15, lk = (l >> 4) * 8;
    for (int kk = 0; kk < 512; kk += 32) {
        __syncthreads();
        uint4 av[2], bv[2];
#pragma unroll
        for (int s = 0; s < 2; ++s) {
            int chunk = tid + s * 256;
            int row = chunk >> 2;
            int colh = (chunk & 3) * 8;
            av[s] = *(const uint4*)&A[((size_t)(bm * 128 + row)) * 512 + kk + colh];
            bv[s] = *(const uint4*)&Bw[((size_t)(bn * 128 + row)) * 512 + kk + colh];
        }
#pragma unroll
        for (int s = 0; s < 2; ++s) {
            int chunk = tid + s * 256;
            *(uint4*)&As[chunk * 8] = av[s];
            *(uint4*)&Bs[chunk * 8] = bv[s];
        }
        __syncthreads();
        half8_t af[4], bf[4];
#pragma unroll
        for (int m = 0; m < 4; ++m)
            af[m] = *(const half8_t*)&As[(wr * 64 + m * 16 + lr) * 32 + lk];
#pragma unroll
        for (int n = 0; n < 4; ++n)
            bf[n] = *(const half8_t*)&Bs[(wc * 64 + n * 16 + lr) * 32 + lk];
#pragma unroll
        for (int m = 0; m < 4; ++m)
#pragma unroll
            for (int n = 0; n < 4; ++n)
                acc[m][n] = __builtin_amdgcn_mfma_f32_16x16x32_f16(af[m], bf[n], acc[m][n], 0, 0, 0);
    }
    float bz[4];
#pragma unroll
    for (int n = 0; n < 4; ++n) bz[n] = bias[bn * 128 + wc * 64 + n * 16 + lr];
    const int lq = l >> 4;
#pragma unroll
    for (int m = 0; m < 4; ++m)
#pragma unroll
        for (int n = 0; n < 4; ++n)
#pragma unroll
            for (int e = 0; e < 4; ++e) {
                int row = bm * 128 + wr * 64 + m * 16 + lq * 4 + e;
                int col = bn * 128 + wc * 64 + n * 16 + lr;
                C[(size_t)row * 512 + col] = (f16)(acc[m][n][e] + bz[n]);
            }
}

// ---------------- fused 3-stage pipeline, XCD-segregated ----------------
#define FOR_Q(M, c, r) M(c, r, 0) M(c, r, 1) M(c, r, 2) M(c, r, 3)
#define FOR_R8(M, c) FOR_Q(M, c, 0) FOR_Q(M, c, 1) FOR_Q(M, c, 2) FOR_Q(M, c, 3) \
                     FOR_Q(M, c, 4) FOR_Q(M, c, 5) FOR_Q(M, c, 6) FOR_Q(M, c, 7)
#define FOR_ALL(M) FOR_R8(M, 0) FOR_R8(M, 1) FOR_R8(M, 2) FOR_R8(M, 3) \
                   FOR_R8(M, 4) FOR_R8(M, 5) FOR_R8(M, 6)

#define DECLW(c, r, q) uint32_t W_##c##_##r##_##q;
#define LOADW(c, r, q) W_##c##_##r##_##q = wpb[(size_t)(((c)*32 + (r)*4 + (q)) * 512) + tid];
#define DOTQ(c, r, q) a##r = fdot2u(W_##c##_##r##_##q, hq##q, a##r);

#define CHUNK(c)                                                   \
    {                                                              \
        uint4 hv = *(const uint4*)(hrow + (c) * 4);                \
        uint32_t hq0 = hv.x, hq1 = hv.y, hq2 = hv.z, hq3 = hv.w;   \
        FOR_R8(DOTQ, c)                                            \
    }

#define LROW(r)                                                    \
    {                                                              \
        uint4 wv = *(const uint4*)&wlds[((r) * 512 + tid) * 4];    \
        a##r = fdot2u(wv.x, hq0, a##r);                            \
        a##r = fdot2u(wv.y, hq1, a##r);                            \
        a##r = fdot2u(wv.z, hq2, a##r);                            \
        a##r = fdot2u(wv.w, hq3, a##r);                            \
    }

#define CHUNKL                                                     \
    {                                                              \
        uint4 hv = *(const uint4*)(hrow + 7 * 4);                  \
        uint32_t hq0 = hv.x, hq1 = hv.y, hq2 = hv.z, hq3 = hv.w;   \
        LROW(0) LROW(1) LROW(2) LROW(3)                            \
        LROW(4) LROW(5) LROW(6) LROW(7)                            \
    }

#define TREE8                                                                 \
    float b0 = (m0 ? a1 : a0) + __shfl_xor(m0 ? a0 : a1, 1);                  \
    float b1 = (m0 ? a3 : a2) + __shfl_xor(m0 ? a2 : a3, 1);                  \
    float b2 = (m0 ? a5 : a4) + __shfl_xor(m0 ? a4 : a5, 1);                  \
    float b3 = (m0 ? a7 : a6) + __shfl_xor(m0 ? a6 : a7, 1);                  \
    float c0 = (m1 ? b1 : b0) + __shfl_xor(m1 ? b0 : b1, 2);                  \
    float c1 = (m1 ? b3 : b2) + __shfl_xor(m1 ? b2 : b3, 2);                  \
    float d0 = (m2 ? c1 : c0) + __shfl_xor(m2 ? c0 : c1, 4);

#define HB_STRIDE 72    // 64 f16 + 8 pad per k-group: bank-conflict-free uint4 reads
#define XROW 576        // xin row stride in f16 = 8 k-groups x 72

// 256 blocks; xcd = bid&7 (round-robin heuristic): {0,1}->stage0 (rnn L0, producer-only),
// {2,3}->stage1 (proj, consumer+producer), {4,5}->stage2 (rnn L1, consumer-only), {6,7} exit.
// Stage-0 XCDs see ZERO L2 invalidates; consumer invalidates land on L2s nobody's step
// depends on. Producer: RELEASE flag store (wbl2). Consumer: ACQUIRE fence after spin (inv).
__global__ __launch_bounds__(512)
__attribute__((amdgpu_waves_per_eu(2, 2)))
void fused3(const f16* __restrict__ xp0, const uint32_t* __restrict__ wp0,
            const uint32_t* __restrict__ wpih1, const uint32_t* __restrict__ wp1,
            const float* __restrict__ bs1,
            f16* __restrict__ h0seq, f16* __restrict__ xp1seq,
            f16* __restrict__ h1last,
            int* __restrict__ flag1, int* __restrict__ flag2) {
    const int xcd = blockIdx.x & 7;
    if (xcd >= 6) return;
    const int stage = xcd >> 1;                  // 0,1,2
    const int row = (xcd & 1) * 32 + (blockIdx.x >> 3);   // 0..63, unique per stage
    const int tid = threadIdx.x;
    const int kg = tid & 7;
    __shared__ alignas(16) f16 hbuf[2][8 * HB_STRIDE];
    __shared__ uint32_t wlds[8 * 512 * 4];            // 64 KB
    __shared__ alignas(16) f16 xin[2][16 * XROW];     // 36 KB double-buffered input chunks

    const uint32_t* wpb = (stage == 0) ? wp0 : (stage == 1) ? wpih1 : wp1;
    const f16* inbase = (stage == 0) ? xp0 + (size_t)row * 262144
                       : (stage == 1) ? h0seq + (size_t)row * 262144
                                      : xp1seq + (size_t)row * 262144;
    f16* outbase = (stage == 0) ? h0seq + (size_t)row * 262144
                  : (stage == 1) ? xp1seq + (size_t)row * 262144
                                 : h1last + (size_t)row * 512;
    int* flIn  = (stage == 1) ? flag1 + row : (stage == 2) ? flag2 + row : nullptr;
    int* flOut = (stage == 0) ? flag1 + row : (stage == 1) ? flag2 + row : nullptr;

    // stage 16-step input chunk g into padded xin[g&1] (cached loads + b128 LDS writes)
    // slot s: row rw = s>>6, pos = s&63 (16B units); f16 idx (g*16+rw)*512 + pos*8
    // -> xin f16 idx rw*XROW + (pos>>3)*72 + (pos&7)*8
    auto stageChunk = [&](int g) {
#pragma unroll
        for (int s2 = 0; s2 < 2; ++s2) {
            int s = tid + s2 * 512;
            int rw = s >> 6, pos = s & 63;
            uint4 v = *(const uint4*)&inbase[(size_t)(g * 16 + rw) * 512 + pos * 8];
            *(uint4*)&xin[g & 1][rw * XROW + (pos >> 3) * 72 + (pos & 7) * 8] = v;
        }
    };

    FOR_ALL(DECLW)
    FOR_ALL(LOADW)
#pragma unroll
    for (int i = 0; i < 8; ++i) {
        uint4 v = *(const uint4*)&wpb[(size_t)224 * 512 + (size_t)(i * 512 + tid) * 4];
        *(uint4*)&wlds[(i * 512 + tid) * 4] = v;
    }
    for (int i = tid; i < 2 * 8 * HB_STRIDE; i += 512) ((f16*)hbuf)[i] = (f16)0.f;
    float bsv = (stage == 1) ? bs1[tid] : 0.f;

    if (flIn) {
        spin_ge(flIn, 1);
        acq_fence();
    }
    stageChunk(0);
    __syncthreads();

    const bool m0 = (tid & 1), m1 = (tid & 2), m2 = (tid & 4);
    const int hwpos = (tid >> 6) * HB_STRIDE + (tid & 63);

    if (stage == 1) {
        // ---- projection: no recurrence -> barrier-free within each 16-step chunk ----
        for (int c = 0; c < 32; ++c) {
            for (int lt = 0; lt < 16; ++lt) {
                if (lt == 12 && c < 31) {
                    spin_ge(flIn, c + 2);
                    acq_fence();
                    stageChunk(c + 1);                 // other buffer; chunk barrier below
                }
                float a0 = 0.f, a1 = 0.f, a2 = 0.f, a3 = 0.f;
                float a4 = 0.f, a5 = 0.f, a6 = 0.f, a7 = 0.f;
                const uint32_t* hrow = (const uint32_t*)&xin[c & 1][lt * XROW + kg * 72];
                CHUNKL
                CHUNK(0) CHUNK(1) CHUNK(2) CHUNK(3) CHUNK(4) CHUNK(5) CHUNK(6)
                TREE8
                outbase[(size_t)(c * 16 + lt) * 512 + tid] = (f16)(d0 + bsv);
            }
            __syncthreads();                           // drains stores + LDS writes
            if (tid == 0)
                __hip_atomic_store(flOut, c + 1, __ATOMIC_RELEASE, __HIP_MEMORY_SCOPE_AGENT);
        }
    } else {
        // ---- recurrence stages (R8 core): one barrier per step ----
        int p = 0;
        for (int t = 0; t < 512; ++t) {
            const int c = t >> 4, lt = t & 15;
            if (lt == 12 && c < 31) {
                if (flIn) {
                    spin_ge(flIn, c + 2);
                    acq_fence();
                }
                stageChunk(c + 1);
            }
            float xpv = (float)xin[c & 1][lt * XROW + (tid >> 6) * 72 + (tid & 63)];

            float a0 = 0.f, a1 = 0.f, a2 = 0.f, a3 = 0.f;
            float a4 = 0.f, a5 = 0.f, a6 = 0.f, a7 = 0.f;
            const uint32_t* hrow = (const uint32_t*)&hbuf[p][kg * HB_STRIDE];
            CHUNKL
            CHUNK(0) CHUNK(1) CHUNK(2) CHUNK(3) CHUNK(4) CHUNK(5) CHUNK(6)
            TREE8
            float s = d0 + xpv;
            float e = __expf(2.0f * s);
            f16 hh = (f16)(1.0f - 2.0f / (1.0f + e));
            hbuf[p ^ 1][hwpos] = hh;
            if (stage == 0) outbase[(size_t)t * 512 + tid] = hh;
            else if (t == 511) outbase[tid] = hh;
            __syncthreads();                           // drains global stores too
            if (stage == 0 && lt == 15 && tid == 0)
                __hip_atomic_store(flOut, c + 1, __ATOMIC_RELEASE, __HIP_MEMORY_SCOPE_AGENT);
            p ^= 1;
        }
    }
}

// ---------------- final FC ----------------
__global__ __launch_bounds__(512) void fc_kernel(const f16* __restrict__ h1,
                                                 const float* __restrict__ Wfc,
                                                 const float* __restrict__ bfc,
                                                 float* __restrict__ out) {
    int b = blockIdx.x, tid = threadIdx.x;
    __shared__ float red[8];
    float v = (float)h1[(size_t)b * 512 + tid] * Wfc[tid];
#pragma unroll
    for (int off = 32; off > 0; off >>= 1) v += __shfl_down(v, off, 64);
    if ((tid & 63) == 0) red[tid >> 6] = v;
    __syncthreads();
    if (tid == 0) {
        float s = bfc[0];
#pragma unroll
        for (int g = 0; g < 8; ++g) s += red[g];
        out[b] = s;
    }
}

extern "C" void kernel_launch(void* const* d_in, const int* in_sizes, int n_in,
                              void* d_out, int out_size, void* d_ws, size_t ws_size,
                              hipStream_t stream) {
    const float* x    = (const float*)d_in[0];
    const float* Wih0 = (const float*)d_in[1];
    const float* Whh0 = (const float*)d_in[2];
    const float* bih0 = (const float*)d_in[3];
    const float* bhh0 = (const float*)d_in[4];
    const float* Wih1 = (const float*)d_in[5];
    const float* Whh1 = (const float*)d_in[6];
    const float* bih1 = (const float*)d_in[7];
    const float* bhh1 = (const float*)d_in[8];
    const float* Wfc  = (const float*)d_in[9];
    const float* bfc  = (const float*)d_in[10];
    float* out = (float*)d_out;

    char* ws = (char*)d_ws;
    size_t off = 0;
    auto alloc = [&](size_t bytes) -> void* {
        void* p = ws + off;
        off += (bytes + 255) & ~(size_t)255;
        return p;
    };
    const size_t MTD = (size_t)64 * 512 * 512;
    f16* x16    = (f16*)alloc(MTD * 2);
    f16* h016   = (f16*)alloc(MTD * 2);
    f16* xpb    = (f16*)alloc(MTD * 2);
    f16* xp1b   = (f16*)alloc(MTD * 2);
    f16* wih016 = (f16*)alloc((size_t)512 * 512 * 2);
    uint32_t* wp0   = (uint32_t*)alloc((size_t)131072 * 4);
    uint32_t* wp1   = (uint32_t*)alloc((size_t)131072 * 4);
    uint32_t* wpih1 = (uint32_t*)alloc((size_t)131072 * 4);
    float* bs0 = (float*)alloc(512 * 4);
    float* bs1 = (float*)alloc(512 * 4);
    f16* h1last = (f16*)alloc((size_t)64 * 512 * 2);
    int* flags = (int*)alloc(128 * 4);   // flag1[64] + flag2[64]

    // prep
    cvt_kernel<<<2048, 256, 0, stream>>>(x, x16, (int)(MTD / 4));
    cvt_kernel<<<256, 256, 0, stream>>>(Wih0, wih016, 512 * 512 / 4);
    bsum_kernel<<<1, 512, 0, stream>>>(bih0, bhh0, bs0);
    bsum_kernel<<<1, 512, 0, stream>>>(bih1, bhh1, bs1);
    pack_whh<<<512, 256, 0, stream>>>(Whh0, wp0);
    pack_whh<<<512, 256, 0, stream>>>(Whh1, wp1);
    pack_whh<<<512, 256, 0, stream>>>(Wih1, wpih1);
    (void)hipMemsetAsync(flags, 0, 128 * 4, stream);

    // layer-0 xproj GEMM, then the fused 3-stage pipeline, then the head
    gemm_xp<<<1024, 256, 0, stream>>>(x16, wih016, bs0, xpb);
    fused3<<<256, 512, 0, stream>>>(xpb, wp0, wpih1, wp1, bs1,
                                    h016, xp1b, h1last, flags, flags + 64);
    fc_kernel<<<64, 512, 0, stream>>>(h1last, Wfc, bfc, out);
}